// Round 7
// baseline (442.228 us; speedup 1.0000x reference)
//
#include <hip/hip_runtime.h>
#include <hip/hip_bf16.h>

#define B_   32
#define NS_  16
#define NP_  8
#define C_   256
#define T_   128
#define M_   (T_*T_)      // 16384
#define NF_  144          // 128 phrase rows + 16 sentence rows
#define MT_  128          // m-columns per block
#define KC_  32           // k per chunk
#define NCH_ (C_/KC_)     // 8 chunks

typedef __attribute__((ext_vector_type(4))) float f32x4;
typedef __attribute__((ext_vector_type(8))) short s16x8;
typedef __attribute__((ext_vector_type(4))) int   i32x4;
typedef __attribute__((ext_vector_type(2))) int   i32x2;

// V LDS geometry (shorts): [8 subtiles][32 kk][20] + pad — proven layout
#define KSTR 20
#define SUBT 644
#define VBUF 5152          // shorts per V chunk buffer (10304 B)
#define ABUF_B  9216       // bytes per A chunk (144 rows x 32 shorts)
#define ABUF_DW 2304

// LDS byte map (total 39040 B -> 4 blocks/CU):
//   [0,     20608)  vb  : 2 x VBUF shorts
//   [20608, 39040)  ab  : 2 x 9216 B A buffers (filled by global_load_lds DMA)
//   epilogue overlays ab region (as round-0):
//     pbuf 20608..24704, rnl 24704..25216, att 25216..33664,
//     pwl 33664..34176, pml 34176..34688
#define LDS_BYTES 39040
#define AB_OFF    20608

__device__ __forceinline__ short f2bf(float f) {
  unsigned u = __builtin_bit_cast(unsigned, f);
  u += 0x7fffu + ((u >> 16) & 1u);
  return (short)(u >> 16);
}
__device__ __forceinline__ int cvt_pk_bf16(float a, float b) {
  int d;
  asm("v_cvt_pk_bf16_f32 %0, %1, %2" : "=v"(d) : "v"(a), "v"(b));
  return d;  // lo16 = bf16(a), hi16 = bf16(b)
}
__device__ __forceinline__ float sigm(float z) { return 1.0f / (1.0f + __expf(-z)); }

// ---------------- kernel 1: normalize features -> bf16, chunk-major layout ----------------
__global__ void prep_feats(const float* __restrict__ sf, const float* __restrict__ pf,
                           short* __restrict__ Fb) {
  const int bs = blockIdx.x;          // b*16 + s
  const int b  = bs >> 4, s = bs & 15;
  const int t  = threadIdx.x;         // c index 0..255
  __shared__ float red[4];
  const int kc   = t >> 5;
  const int kk   = t & 31;
  const int half = kk >> 4;
  const int g    = (kk & 15) >> 2;
  const int j    = kk & 3;
  const int pos  = 8 * g + 4 * half + j;
  for (int v = 0; v < 9; ++v) {
    float x = (v < 8) ? pf[(((size_t)bs) * NP_ + v) * C_ + t]
                      : sf[((size_t)bs) * C_ + t];
    float ss = x * x;
    #pragma unroll
    for (int off = 32; off; off >>= 1) ss += __shfl_xor(ss, off);
    __syncthreads();
    if ((t & 63) == 0) red[t >> 6] = ss;
    __syncthreads();
    const float tot = red[0] + red[1] + red[2] + red[3];
    const float rn = 1.0f / fmaxf(sqrtf(tot), 1e-12f);
    const int row = (v < 8) ? (s * NP_ + v) : (128 + s);
    Fb[(((size_t)(b * 8 + kc)) * NF_ + row) * 32 + pos] = f2bf(x * rn);
  }
}

// ---------------- kernel 2: fused GEMM + norm + epilogue ----------------
// R4's counted-vmcnt pipeline (proved 4.1 TB/s) + R0's cached epilogue (byte-clean):
//  - A chunks stream global->LDS via global_load_lds (no regs, rides vmcnt queue)
//  - V chunk k+2 issued before the barrier and kept IN FLIGHT across it
//  - per-chunk sync: s_waitcnt vmcnt(4) lgkmcnt(0) + raw s_barrier
__global__ void __launch_bounds__(256, 4) trm_main(
    const float* __restrict__ V,   // (B,C,T,T)
    const int* __restrict__ FbD,   // (B,8,144,32) bf16 as dwords
    const float* __restrict__ pw,
    const float* __restrict__ pm,
    float* __restrict__ out0,      // (B,NS,T,T)
    float* __restrict__ out1) {    // (B,NS,NP,T,T)
  __shared__ __align__(16) char smem[LDS_BYTES];
  short* vb  = (short*)smem;
  short* abS = (short*)(smem + AB_OFF);
  float* pbuf = (float*)(smem + AB_OFF);
  float* rnl  = (float*)(smem + AB_OFF + 4096);
  float* att  = (float*)(smem + AB_OFF + 4608);
  float* pwl  = (float*)(smem + AB_OFF + 13056);
  float* pml  = (float*)(smem + AB_OFF + 13568);

  const int tid  = threadIdx.x;
  const int b    = blockIdx.y;
  const int tile = blockIdx.x;
  const int m0   = tile * MT_;

  // V staging coords
  const int c4 = tid & 31;
  const int q  = tid >> 5;
  const size_t vbase = ((size_t)b * C_) * M_ + m0 + c4 * 4;
  const int smt  = c4 >> 2;
  const int scc0 = (c4 & 3) * 4;

  // wave coords
  const int lane = tid & 63;
  const int w  = tid >> 6;
  const int g  = lane >> 4;
  const int cc = lane & 15;

  f32x4 acc[9][2];
  #pragma unroll
  for (int i = 0; i < 9; ++i) {
    #pragma unroll
    for (int n = 0; n < 2; ++n) acc[i][n] = (f32x4){0.f, 0.f, 0.f, 0.f};
  }

  float4 rA[4], rB[4];
  float ssq0 = 0.f, ssq1 = 0.f, ssq2 = 0.f, ssq3 = 0.f;

  const char* Ag = (const char*)FbD + (size_t)b * 8 * ABUF_B;

  // ---- A chunk DMA: linear copy global->LDS, per-wave 1KB segments (3 vmem ops/wave)
  #define LOADA(kcn, bufn) do {                                                      \
    const char* _s0 = Ag + (size_t)(kcn) * ABUF_B + w * 1024 + lane * 16;            \
    char* _d0 = smem + AB_OFF + (bufn) * ABUF_B + w * 1024;                          \
    __builtin_amdgcn_global_load_lds(                                                \
        (const __attribute__((address_space(1))) void*)_s0,                          \
        (__attribute__((address_space(3))) void*)_d0, 16, 0, 0);                     \
    __builtin_amdgcn_global_load_lds(                                                \
        (const __attribute__((address_space(1))) void*)(_s0 + 4096),                 \
        (__attribute__((address_space(3))) void*)(_d0 + 4096), 16, 0, 0);            \
    const char* _s2 = Ag + (size_t)(kcn) * ABUF_B + 8192 + w * 256 + lane * 4;       \
    char* _d2 = smem + AB_OFF + (bufn) * ABUF_B + 8192 + w * 256;                    \
    __builtin_amdgcn_global_load_lds(                                                \
        (const __attribute__((address_space(1))) void*)_s2,                          \
        (__attribute__((address_space(3))) void*)_d2, 4, 0, 0);                      \
  } while (0)

  #define FENCE() asm volatile("" ::: "memory")

  #define LOADV(R, kcn) do {                                                         \
    _Pragma("unroll")                                                                \
    for (int _i = 0; _i < 4; ++_i)                                                   \
      R[_i] = *(const float4*)(V + vbase + (size_t)((kcn) * KC_ + q + _i * 8) * M_); \
  } while (0)

  #define PACKV(R, bufn) do {                                                        \
    _Pragma("unroll")                                                                \
    for (int _i = 0; _i < 4; ++_i) {                                                 \
      const int _kk = q + _i * 8;                                                    \
      ssq0 += R[_i].x * R[_i].x; ssq1 += R[_i].y * R[_i].y;                          \
      ssq2 += R[_i].z * R[_i].z; ssq3 += R[_i].w * R[_i].w;                          \
      i32x2 _pk = {cvt_pk_bf16(R[_i].x, R[_i].y), cvt_pk_bf16(R[_i].z, R[_i].w)};    \
      *(i32x2*)(&vb[(bufn) * VBUF + smt * SUBT + _kk * KSTR + scc0]) = _pk;          \
    }                                                                                \
  } while (0)

  #define KBARN(n) do {                                                              \
    asm volatile("s_waitcnt vmcnt(" #n ") lgkmcnt(0)" ::: "memory");                 \
    __builtin_amdgcn_s_barrier();                                                    \
    asm volatile("" ::: "memory");                                                   \
  } while (0)

  #define COMPUTE(bufn, kcn) do {                                                    \
    s16x8 bf[2];                                                                     \
    _Pragma("unroll")                                                                \
    for (int _n = 0; _n < 2; ++_n) {                                                 \
      const int _mt = 2 * w + _n;                                                    \
      const int _base = (bufn) * VBUF + _mt * SUBT + cc;                             \
      _Pragma("unroll")                                                              \
      for (int _j = 0; _j < 4; ++_j) {                                               \
        bf[_n][_j]     = vb[_base + (4 * g + _j) * KSTR];                            \
        bf[_n][_j + 4] = vb[_base + (16 + 4 * g + _j) * KSTR];                       \
      }                                                                              \
    }                                                                                \
    const short* _Arow = abS + (bufn) * (ABUF_DW * 2) + cc * 32 + g * 8;             \
    _Pragma("unroll")                                                                \
    for (int _ft = 0; _ft < 9; ++_ft) {                                              \
      const s16x8 _af = *(const s16x8*)(_Arow + _ft * (16 * 32));                    \
      acc[_ft][0] = __builtin_amdgcn_mfma_f32_16x16x32_bf16(_af, bf[0], acc[_ft][0], 0, 0, 0); \
      acc[_ft][1] = __builtin_amdgcn_mfma_f32_16x16x32_bf16(_af, bf[1], acc[_ft][1], 0, 0, 0); \
    }                                                                                \
  } while (0)

  // ---- prologue
  LOADA(0, 0);            // A0 -> ab0 (DMA, oldest in queue)
  FENCE();
  LOADV(rA, 0);           // V0 -> regs
  PACKV(rA, 0);           // consume V0 (A0 is older -> also complete after this wait)
  LOADV(rA, 1);           // V1 in flight
  KBARN(4);               // keep V1 flying; nothing else outstanding

  // ---- main loop: iter kc reads vb/ab[kc&1], issues A(kc+1) DMA + V(kc+2),
  //                 packs V(kc+1), then counted-vmcnt barrier.
  #pragma unroll
  for (int kc = 0; kc < NCH_; ++kc) {
    if (kc < NCH_ - 1) { LOADA(kc + 1, (kc + 1) & 1); FENCE(); }
    if (kc < NCH_ - 2) {
      if (kc & 1) { LOADV(rA, kc + 2); } else { LOADV(rB, kc + 2); }
      FENCE();
    }
    COMPUTE(kc & 1, kc);
    if (kc < NCH_ - 1) {
      if (kc & 1) { PACKV(rB, (kc + 1) & 1); } else { PACKV(rA, (kc + 1) & 1); }
      if (kc < NCH_ - 2) { KBARN(4); } else { KBARN(0); }
    }
  }

  __syncthreads();   // ab region about to be overlaid by epilogue buffers

  // ---- column norms
  {
    f32x4 p = {ssq0, ssq1, ssq2, ssq3};
    *(f32x4*)(&pbuf[q * 128 + c4 * 4]) = p;
  }
  if (tid < 128) { pwl[tid] = pw[b * 128 + tid]; pml[tid] = pm[b * 128 + tid]; }
  __syncthreads();
  if (tid < 128) {
    float ss = 0.f;
    #pragma unroll
    for (int qq = 0; qq < 8; ++qq) ss += pbuf[qq * 128 + tid];
    rnl[tid] = 1.0f / fmaxf(sqrtf(ss), 1e-12f);
  }
  __syncthreads();

  // ---- epilogue: phrase outputs + ph_att (round-0 verbatim, cached stores)
  #pragma unroll
  for (int n = 0; n < 2; ++n) {
    const int col = (2 * w + n) * 16 + cc;
    const float rn = rnl[col];
    const int m = m0 + col;
    const float msk = (col >= tile) ? 1.0f : 0.0f;
    #pragma unroll
    for (int ft = 0; ft < 8; ++ft) {
      float pa = 0.f;
      #pragma unroll
      for (int rr = 0; rr < 4; ++rr) {
        const int f = ft * 16 + 4 * g + rr;
        const float raw = acc[ft][n][rr] * rn;
        out1[(((size_t)(b * NS_ + (f >> 3)) * NP_ + (f & 7)) << 14) + m] =
            sigm(10.0f * raw) * msk * pml[f];
        pa += pwl[f] * raw;
      }
      pa += __shfl_xor(pa, 16);
      if ((g & 1) == 0) att[(2 * ft + (g >> 1)) * 132 + col] = pa;
    }
  }
  __syncthreads();
  // ---- sentence output
  #pragma unroll
  for (int n = 0; n < 2; ++n) {
    const int col = (2 * w + n) * 16 + cc;
    const float rn = rnl[col];
    const int m = m0 + col;
    const float msk = (col >= tile) ? 1.0f : 0.0f;
    #pragma unroll
    for (int rr = 0; rr < 4; ++rr) {
      const int s = 4 * g + rr;
      const float sfv = acc[8][n][rr] * rn;
      const float pa = att[s * 132 + col];
      out0[(((size_t)(b * NS_ + s)) << 14) + m] = sigm(10.0f * (sfv + 0.5f * pa)) * msk;
    }
  }
}

extern "C" void kernel_launch(void* const* d_in, const int* in_sizes, int n_in,
                              void* d_out, int out_size, void* d_ws, size_t ws_size,
                              hipStream_t stream) {
  const float* V  = (const float*)d_in[0];
  const float* sf = (const float*)d_in[1];
  const float* pf = (const float*)d_in[2];
  const float* pw = (const float*)d_in[3];
  const float* pm = (const float*)d_in[4];
  float* out0 = (float*)d_out;
  float* out1 = out0 + (size_t)B_ * NS_ * M_;
  short* Fb = (short*)d_ws;   // (B,8,144,32) bf16, fragment-ordered

  prep_feats<<<B_ * NS_, 256, 0, stream>>>(sf, pf, Fb);
  dim3 grid(M_ / MT_, B_);
  trm_main<<<grid, 256, 0, stream>>>(V, (const int*)Fb, pw, pm, out0, out1);
}

// Round 8
// 260.577 us; speedup vs baseline: 1.6971x; 1.6971x over previous
//
#include <hip/hip_runtime.h>
#include <hip/hip_bf16.h>

#define B_   32
#define NS_  16
#define NP_  8
#define C_   256
#define T_   128
#define M_   (T_*T_)      // 16384
#define NF_  144          // 128 phrase rows + 16 sentence rows
#define MT_  128          // m-columns per block
#define KC_  32           // k per chunk
#define NCH_ (C_/KC_)     // 8 chunks

typedef __attribute__((ext_vector_type(4))) float f32x4;
typedef __attribute__((ext_vector_type(8))) short s16x8;
typedef __attribute__((ext_vector_type(4))) short s16x4;
typedef __attribute__((ext_vector_type(4))) int   i32x4;
typedef __attribute__((ext_vector_type(2))) int   i32x2;

// V LDS geometry (shorts): [8 subtiles][32 kk][20] + pad — proven in round 1
#define KSTR 20
#define SUBT 644
#define VBUF 5152          // shorts per V chunk buffer (10304 B)
#define ABUF_DW 2304       // dwords per A chunk buffer (9216 B: 144 rows x 32 shorts)

// LDS byte map (total 39040 B -> 4 blocks/CU):
//   [0,     20608)  vb  : 2 x VBUF shorts
//   [20608, 39040)  ab  : 2 x 9216 B A buffers
//   epilogue overlays ab region:
//     pbuf 20608..24704, rnl 24704..25216, att 25216..33664,
//     pwl 33664..34176, pml 34176..34688
#define LDS_BYTES 39040
#define AB_OFF    20608

__device__ __forceinline__ short f2bf(float f) {
  unsigned u = __builtin_bit_cast(unsigned, f);
  u += 0x7fffu + ((u >> 16) & 1u);
  return (short)(u >> 16);
}
__device__ __forceinline__ int cvt_pk_bf16(float a, float b) {
  int d;
  asm("v_cvt_pk_bf16_f32 %0, %1, %2" : "=v"(d) : "v"(a), "v"(b));
  return d;  // lo16 = bf16(a), hi16 = bf16(b)
}
__device__ __forceinline__ float sigm(float z) { return 1.0f / (1.0f + __expf(-z)); }

// ---------------- kernel 1: normalize features -> bf16, chunk-major layout ----------------
// Fb layout: [b][kc][row][32 shorts], within 32: pos = 8*g + 4*half + j for
// k = 32*kc + half*16 + 4*g + j  (std MFMA slot order per 16B fragment)
__global__ void prep_feats(const float* __restrict__ sf, const float* __restrict__ pf,
                           short* __restrict__ Fb) {
  const int bs = blockIdx.x;          // b*16 + s
  const int b  = bs >> 4, s = bs & 15;
  const int t  = threadIdx.x;         // c index 0..255
  __shared__ float red[4];
  const int kc   = t >> 5;
  const int kk   = t & 31;
  const int half = kk >> 4;
  const int g    = (kk & 15) >> 2;
  const int j    = kk & 3;
  const int pos  = 8 * g + 4 * half + j;
  for (int v = 0; v < 9; ++v) {
    float x = (v < 8) ? pf[(((size_t)bs) * NP_ + v) * C_ + t]
                      : sf[((size_t)bs) * C_ + t];
    float ss = x * x;
    #pragma unroll
    for (int off = 32; off; off >>= 1) ss += __shfl_xor(ss, off);
    __syncthreads();
    if ((t & 63) == 0) red[t >> 6] = ss;
    __syncthreads();
    const float tot = red[0] + red[1] + red[2] + red[3];
    const float rn = 1.0f / fmaxf(sqrtf(tot), 1e-12f);
    const int row = (v < 8) ? (s * NP_ + v) : (128 + s);
    Fb[(((size_t)(b * 8 + kc)) * NF_ + row) * 32 + pos] = f2bf(x * rn);
  }
}

// ---------------- kernel 2: fused GEMM + norm + epilogue ----------------
// Round-0 kernel verbatim, plus XCD-chunked block swizzle:
//   linear id lid -> xcd = lid%8 (HW round-robin), slot = lid/8;
//   new id = xcd*512 + slot  => each XCD executes consecutive (tile) indices
//   of the same b, so its co-resident blocks sweep V/out1 in contiguous
//   address spans (DRAM page locality) and share one A panel in its L2.
__global__ void __launch_bounds__(256, 4) trm_main(
    const float* __restrict__ V,   // (B,C,T,T)
    const int* __restrict__ FbD,   // (B,8,144,32) bf16 as dwords
    const float* __restrict__ pw,
    const float* __restrict__ pm,
    float* __restrict__ out0,      // (B,NS,T,T)
    float* __restrict__ out1) {    // (B,NS,NP,T,T)
  __shared__ __align__(16) char smem[LDS_BYTES];
  short* vb  = (short*)smem;
  int*   abI = (int*)(smem + AB_OFF);
  short* abS = (short*)(smem + AB_OFF);
  float* pbuf = (float*)(smem + AB_OFF);
  float* rnl  = (float*)(smem + AB_OFF + 4096);
  float* att  = (float*)(smem + AB_OFF + 4608);
  float* pwl  = (float*)(smem + AB_OFF + 13056);
  float* pml  = (float*)(smem + AB_OFF + 13568);

  const int tid  = threadIdx.x;
  // ---- XCD-chunked swizzle (bijective: 4096 = 8 * 512)
  const int lid  = blockIdx.x + (blockIdx.y << 7);   // 0..4095
  const int nl   = ((lid & 7) << 9) | (lid >> 3);    // xcd*512 + slot
  const int tile = nl & 127;
  const int b    = nl >> 7;
  const int m0   = tile * MT_;

  // V staging coords
  const int c4 = tid & 31;
  const int q  = tid >> 5;
  const size_t vbase = ((size_t)b * C_) * M_ + m0 + c4 * 4;
  const int smt  = c4 >> 2;
  const int scc0 = (c4 & 3) * 4;

  // wave coords
  const int lane = tid & 63;
  const int w  = tid >> 6;
  const int g  = lane >> 4;
  const int cc = lane & 15;

  f32x4 acc[9][2];
  #pragma unroll
  for (int i = 0; i < 9; ++i) {
    #pragma unroll
    for (int n = 0; n < 2; ++n) acc[i][n] = (f32x4){0.f, 0.f, 0.f, 0.f};
  }

  float4 r[4];
  i32x4 a0, a1;
  int a2;
  float ssq0 = 0.f, ssq1 = 0.f, ssq2 = 0.f, ssq3 = 0.f;

  const int* AbBase = FbD + (size_t)b * 8 * ABUF_DW;

  // ---- LOAD chunk 0 (V + A)
  #pragma unroll
  for (int i = 0; i < 4; ++i) r[i] = *(const float4*)(V + vbase + (size_t)(q + i * 8) * M_);
  {
    const int* Ab = AbBase;
    a0 = *(const i32x4*)(Ab + tid * 4);
    a1 = *(const i32x4*)(Ab + 1024 + tid * 4);
    a2 = Ab[2048 + tid];
  }
  // ---- WRITE chunk 0 -> buf 0
  #pragma unroll
  for (int i = 0; i < 4; ++i) {
    const int kk = q + i * 8;
    ssq0 += r[i].x * r[i].x; ssq1 += r[i].y * r[i].y;
    ssq2 += r[i].z * r[i].z; ssq3 += r[i].w * r[i].w;
    i32x2 pk = {cvt_pk_bf16(r[i].x, r[i].y), cvt_pk_bf16(r[i].z, r[i].w)};
    *(i32x2*)(&vb[smt * SUBT + kk * KSTR + scc0]) = pk;
  }
  {
    int* Ad = abI;
    *(i32x4*)(Ad + tid * 4) = a0;
    *(i32x4*)(Ad + 1024 + tid * 4) = a1;
    Ad[2048 + tid] = a2;
  }
  __syncthreads();

  int cur = 0;
  for (int kc = 0; kc < NCH_; ++kc) {
    // prefetch next chunk (V + A) into registers
    if (kc < NCH_ - 1) {
      #pragma unroll
      for (int i = 0; i < 4; ++i)
        r[i] = *(const float4*)(V + vbase + (size_t)((kc + 1) * KC_ + q + i * 8) * M_);
      const int* Ab = AbBase + (kc + 1) * ABUF_DW;
      a0 = *(const i32x4*)(Ab + tid * 4);
      a1 = *(const i32x4*)(Ab + 1024 + tid * 4);
      a2 = Ab[2048 + tid];
    }
    // ---- COMPUTE chunk kc
    {
      s16x8 bf[2];
      #pragma unroll
      for (int n = 0; n < 2; ++n) {
        const int mt = 2 * w + n;
        const int base = cur * VBUF + mt * SUBT + cc;
        #pragma unroll
        for (int j = 0; j < 4; ++j) {
          bf[n][j]     = vb[base + (4 * g + j) * KSTR];
          bf[n][j + 4] = vb[base + (16 + 4 * g + j) * KSTR];
        }
      }
      const short* Arow = abS + cur * (ABUF_DW * 2) + cc * 32 + g * 8;
      #pragma unroll
      for (int ft = 0; ft < 9; ++ft) {
        const s16x8 af = *(const s16x8*)(Arow + ft * (16 * 32));
        acc[ft][0] = __builtin_amdgcn_mfma_f32_16x16x32_bf16(af, bf[0], acc[ft][0], 0, 0, 0);
        acc[ft][1] = __builtin_amdgcn_mfma_f32_16x16x32_bf16(af, bf[1], acc[ft][1], 0, 0, 0);
      }
    }
    // ---- WRITE next chunk -> other buffer
    if (kc < NCH_ - 1) {
      #pragma unroll
      for (int i = 0; i < 4; ++i) {
        const int kk = q + i * 8;
        ssq0 += r[i].x * r[i].x; ssq1 += r[i].y * r[i].y;
        ssq2 += r[i].z * r[i].z; ssq3 += r[i].w * r[i].w;
        i32x2 pk = {cvt_pk_bf16(r[i].x, r[i].y), cvt_pk_bf16(r[i].z, r[i].w)};
        *(i32x2*)(&vb[(cur ^ 1) * VBUF + smt * SUBT + kk * KSTR + scc0]) = pk;
      }
      int* Ad = abI + (cur ^ 1) * ABUF_DW;
      *(i32x4*)(Ad + tid * 4) = a0;
      *(i32x4*)(Ad + 1024 + tid * 4) = a1;
      Ad[2048 + tid] = a2;
      __syncthreads();
      cur ^= 1;
    }
  }

  __syncthreads();   // A region about to be overlaid by epilogue buffers

  // ---- column norms
  {
    f32x4 p = {ssq0, ssq1, ssq2, ssq3};
    *(f32x4*)(&pbuf[q * 128 + c4 * 4]) = p;
  }
  if (tid < 128) { pwl[tid] = pw[b * 128 + tid]; pml[tid] = pm[b * 128 + tid]; }
  __syncthreads();
  if (tid < 128) {
    float ss = 0.f;
    #pragma unroll
    for (int qq = 0; qq < 8; ++qq) ss += pbuf[qq * 128 + tid];
    rnl[tid] = 1.0f / fmaxf(sqrtf(ss), 1e-12f);
  }
  __syncthreads();

  // ---- epilogue: phrase outputs + ph_att
  #pragma unroll
  for (int n = 0; n < 2; ++n) {
    const int col = (2 * w + n) * 16 + cc;
    const float rn = rnl[col];
    const int m = m0 + col;
    const float msk = (col >= tile) ? 1.0f : 0.0f;
    #pragma unroll
    for (int ft = 0; ft < 8; ++ft) {
      float pa = 0.f;
      #pragma unroll
      for (int rr = 0; rr < 4; ++rr) {
        const int f = ft * 16 + 4 * g + rr;
        const float raw = acc[ft][n][rr] * rn;
        out1[(((size_t)(b * NS_ + (f >> 3)) * NP_ + (f & 7)) << 14) + m] =
            sigm(10.0f * raw) * msk * pml[f];
        pa += pwl[f] * raw;
      }
      pa += __shfl_xor(pa, 16);
      if ((g & 1) == 0) att[(2 * ft + (g >> 1)) * 132 + col] = pa;
    }
  }
  __syncthreads();
  // ---- sentence output
  #pragma unroll
  for (int n = 0; n < 2; ++n) {
    const int col = (2 * w + n) * 16 + cc;
    const float rn = rnl[col];
    const int m = m0 + col;
    const float msk = (col >= tile) ? 1.0f : 0.0f;
    #pragma unroll
    for (int rr = 0; rr < 4; ++rr) {
      const int s = 4 * g + rr;
      const float sfv = acc[8][n][rr] * rn;
      const float pa = att[s * 132 + col];
      out0[(((size_t)(b * NS_ + s)) << 14) + m] = sigm(10.0f * (sfv + 0.5f * pa)) * msk;
    }
  }
}

extern "C" void kernel_launch(void* const* d_in, const int* in_sizes, int n_in,
                              void* d_out, int out_size, void* d_ws, size_t ws_size,
                              hipStream_t stream) {
  const float* V  = (const float*)d_in[0];
  const float* sf = (const float*)d_in[1];
  const float* pf = (const float*)d_in[2];
  const float* pw = (const float*)d_in[3];
  const float* pm = (const float*)d_in[4];
  float* out0 = (float*)d_out;
  float* out1 = out0 + (size_t)B_ * NS_ * M_;
  short* Fb = (short*)d_ws;   // (B,8,144,32) bf16, fragment-ordered

  prep_feats<<<B_ * NS_, 256, 0, stream>>>(sf, pf, Fb);
  dim3 grid(M_ / MT_, B_);
  trm_main<<<grid, 256, 0, stream>>>(V, (const int*)Fb, pw, pm, out0, out1);
}